// Round 2
// baseline (215.563 us; speedup 1.0000x reference)
//
#include <hip/hip_runtime.h>
#include <hip/hip_bf16.h>

#define SEQ 512
#define DIM 512
#define NL  64
#define NB  8

typedef float f32x4 __attribute__((ext_vector_type(4)));

// One block per (b, l). 512 blocks x 256 threads.
//   phase 1: stage W[l, :] (4KB) into LDS
//   phase 2: h[i] = dot(head[b,i,:], Wh) + bias[l];  d[j] = dot(dep[b,j,:], Wd)
//            (each thread computes i = t and i = t+256) -> LDS
//   phase 3: stream out[b,l,i,j] = h[i] + d[j], 1 MiB of sequential NT stores.
//            d fragment lives in registers; h comes from an LDS broadcast read.
// b = blockIdx & 7 -> all 64 blocks of a batch land on one XCD (round-robin
// dispatch), so head[b]+dep[b] (2 MiB) stay in that XCD's private L2.
__global__ __launch_bounds__(256) void alab_fused(
    const float* __restrict__ head, const float* __restrict__ dep,
    const float* __restrict__ W, const float* __restrict__ bias,
    float* __restrict__ out)
{
    const int t = threadIdx.x;
    const int b = blockIdx.x & 7;
    const int l = blockIdx.x >> 3;

    __shared__ f32x4 sWh[DIM / 4];   // 2 KB
    __shared__ f32x4 sWd[DIM / 4];   // 2 KB
    __shared__ float sh[SEQ];        // 2 KB
    __shared__ f32x4 sd4[SEQ / 4];   // 2 KB

    // ---- phase 1: stage W row l (1024 floats = 256 float4, fully coalesced)
    {
        const f32x4* W4 = (const f32x4*)(W + (size_t)l * 2 * DIM);
        if (t < 128) sWh[t]       = W4[t];
        else         sWd[t - 128] = W4[t + 0];   // t in [128,256) -> Wd[t-128]
    }
    __syncthreads();

    const float bias_l = bias[l];

    // ---- phase 2: per-thread GEMV rows i = t, t+256
    const f32x4* h4 = (const f32x4*)head + (size_t)b * SEQ * (DIM / 4);
    const f32x4* d4 = (const f32x4*)dep  + (size_t)b * SEQ * (DIM / 4);
    #pragma unroll
    for (int half = 0; half < 2; ++half) {
        const int i = t + half * 256;
        const f32x4* hr = h4 + (size_t)i * (DIM / 4);
        const f32x4* dr = d4 + (size_t)i * (DIM / 4);
        float ah = 0.f, ad = 0.f;
        #pragma unroll 4
        for (int k = 0; k < DIM / 4; ++k) {
            const f32x4 hv = hr[k], dv = dr[k];
            const f32x4 wh = sWh[k], wd = sWd[k];
            ah += hv.x * wh.x + hv.y * wh.y + hv.z * wh.z + hv.w * wh.w;
            ad += dv.x * wd.x + dv.y * wd.y + dv.z * wd.z + dv.w * wd.w;
        }
        sh[i] = ah + bias_l;
        ((float*)sd4)[i] = ad;
    }
    __syncthreads();

    // ---- phase 3: stream the 512x512 tile. Thread t owns float4-column
    // j4 = t&127 (its d value is loop-invariant -> registers) and row-parity
    // t>>7. Per iteration: 1 LDS broadcast read + 4 adds + 1 NT store.
    const int j4 = t & 127;
    const int rh = t >> 7;                      // 0 or 1
    const f32x4 dreg = sd4[j4];
    f32x4* ob = (f32x4*)out + (size_t)(b * NL + l) * SEQ * (SEQ / 4);
    #pragma unroll 8
    for (int ii = 0; ii < SEQ; ii += 2) {
        const int i = ii + rh;
        const float hv = sh[i];                 // same addr across wave: broadcast
        const f32x4 o = dreg + hv;
        __builtin_nontemporal_store(o, &ob[(size_t)i * (SEQ / 4) + j4]);
    }
}

extern "C" void kernel_launch(void* const* d_in, const int* in_sizes, int n_in,
                              void* d_out, int out_size, void* d_ws, size_t ws_size,
                              hipStream_t stream) {
    const float* head = (const float*)d_in[0];
    const float* dep  = (const float*)d_in[1];
    const float* W    = (const float*)d_in[2];
    const float* bias = (const float*)d_in[3];
    float* out = (float*)d_out;

    alab_fused<<<NB * NL, 256, 0, stream>>>(head, dep, W, bias, out);
}

// Round 3
// 159.216 us; speedup vs baseline: 1.3539x; 1.3539x over previous
//
#include <hip/hip_runtime.h>
#include <hip/hip_bf16.h>

#define BATCH 8
#define SEQ   512
#define DIM   512
#define NL    64
#define ITILE 16

typedef float f32x4 __attribute__((ext_vector_type(4)));

// Kernel 1: h[b,l,i] = dot(head[b,i,:], W[l,0:512]) + bias[l]
//           d[b,l,j] = dot(dep[b,j,:],  W[l,512:1024])
// One block per (b, 16-row i-tile). LDS-stage the tile (XOR-swizzled),
// each thread owns 1 i-row x 4 l-rows.  (unchanged from round 1: ~10 us)
__global__ __launch_bounds__(256) void alab_proj(
    const float* __restrict__ head, const float* __restrict__ dep,
    const float* __restrict__ W, const float* __restrict__ bias,
    float* __restrict__ hbuf, float* __restrict__ dbuf)
{
    __shared__ float4 sh[ITILE * (DIM / 4)];   // 32 KB
    __shared__ float4 sd[ITILE * (DIM / 4)];   // 32 KB
    const int t  = threadIdx.x;
    const int b  = blockIdx.x >> 5;            // 32 i-tiles per batch
    const int i0 = (blockIdx.x & 31) * ITILE;

    const float4* h4 = (const float4*)(head + ((size_t)b * SEQ + i0) * DIM);
    const float4* d4 = (const float4*)(dep  + ((size_t)b * SEQ + i0) * DIM);
    #pragma unroll
    for (int u = t; u < ITILE * (DIM / 4); u += 256) {
        const int row = u >> 7, col = u & 127;
        const int sc  = col ^ (row & 7);       // XOR swizzle vs 2KB row stride
        sh[row * 128 + sc] = h4[u];
        sd[row * 128 + sc] = d4[u];
    }
    __syncthreads();

    const int iL = t & 15;
    const int lg = t >> 4;                     // l = lg*4 + r
    const int xm = iL & 7;
    const float4* W4 = (const float4*)W;       // [NL][256] float4

    float acch[4] = {0.f, 0.f, 0.f, 0.f};
    float accd[4] = {0.f, 0.f, 0.f, 0.f};
    for (int k4 = 0; k4 < DIM / 4; ++k4) {
        const float4 hv = sh[iL * 128 + (k4 ^ xm)];
        const float4 dv = sd[iL * 128 + (k4 ^ xm)];
        #pragma unroll
        for (int r = 0; r < 4; ++r) {
            const int l = lg * 4 + r;
            const float4 wh = W4[l * 256 + k4];
            const float4 wd = W4[l * 256 + 128 + k4];
            acch[r] += wh.x * hv.x + wh.y * hv.y + wh.z * hv.z + wh.w * hv.w;
            accd[r] += wd.x * dv.x + wd.y * dv.y + wd.z * dv.z + wd.w * dv.w;
        }
    }

    #pragma unroll
    for (int r = 0; r < 4; ++r) {
        const int l = lg * 4 + r;
        const size_t o = ((size_t)b * NL + l) * SEQ + i0 + iL;
        hbuf[o] = acch[r] + bias[l];           // bias folded into h
        dbuf[o] = accd[r];
    }
}

// Kernel 2: out[((b*NL+l)*SEQ+i)*SEQ+j] = hbuf[row] + dbuf[bl*SEQ+j]
// PLAIN stores (through L2) — the only change vs round 1's 4.3 TB/s version.
// Fixed grid 2048x256 -> exactly 64 iterations/thread, compile-time stride,
// so the compiler can unroll and hoist the loads ahead of the stores.
#define BCAST_BLOCKS 2048
#define BCAST_STRIDE (BCAST_BLOCKS * 256)      // 524288 threads
__global__ __launch_bounds__(256) void alab_bcast(
    const float* __restrict__ hbuf, const float* __restrict__ dbuf,
    float* __restrict__ out)
{
    const f32x4* dv4 = (const f32x4*)dbuf;
    f32x4* out4 = (f32x4*)out;
    const int tid = blockIdx.x * 256 + threadIdx.x;   // 0..524287
    #pragma unroll 4
    for (int it = 0; it < 64; ++it) {
        const size_t idx = (size_t)it * BCAST_STRIDE + tid;
        const int    j4  = (int)(idx & (SEQ / 4 - 1));   // 0..127
        const size_t row = idx >> 7;                     // (b*NL+l)*SEQ + i
        const size_t bl  = row >> 9;                     // b*NL + l
        const float  hv  = hbuf[row];                    // one line/wave, L2-hit
        const f32x4  dv  = dv4[bl * (SEQ / 4) + j4];     // 1KB/wave, L2-hit
        out4[idx] = dv + hv;                             // plain streaming store
    }
}

extern "C" void kernel_launch(void* const* d_in, const int* in_sizes, int n_in,
                              void* d_out, int out_size, void* d_ws, size_t ws_size,
                              hipStream_t stream) {
    const float* head = (const float*)d_in[0];
    const float* dep  = (const float*)d_in[1];
    const float* W    = (const float*)d_in[2];
    const float* bias = (const float*)d_in[3];
    float* out  = (float*)d_out;
    float* hbuf = (float*)d_ws;                          // 1 MiB
    float* dbuf = hbuf + (size_t)BATCH * NL * SEQ;       // 1 MiB

    alab_proj<<<BATCH * (SEQ / ITILE), 256, 0, stream>>>(head, dep, W, bias, hbuf, dbuf);
    alab_bcast<<<BCAST_BLOCKS, 256, 0, stream>>>(hbuf, dbuf, out);
}

// Round 4
// 135.925 us; speedup vs baseline: 1.5859x; 1.1714x over previous
//
#include <hip/hip_runtime.h>
#include <hip/hip_bf16.h>

#define BATCH 8
#define SEQ   512
#define DIM   512
#define NL    64
#define ITILE 16

typedef float f32x4 __attribute__((ext_vector_type(4)));

// Kernel 1 (unchanged, proven ~10us):
//   h[b,l,i] = dot(head[b,i,:], W[l,0:512]) + bias[l]
//   d[b,l,j] = dot(dep[b,j,:],  W[l,512:1024])
__global__ __launch_bounds__(256) void alab_proj(
    const float* __restrict__ head, const float* __restrict__ dep,
    const float* __restrict__ W, const float* __restrict__ bias,
    float* __restrict__ hbuf, float* __restrict__ dbuf)
{
    __shared__ float4 sh[ITILE * (DIM / 4)];   // 32 KB
    __shared__ float4 sd[ITILE * (DIM / 4)];   // 32 KB
    const int t  = threadIdx.x;
    const int b  = blockIdx.x >> 5;
    const int i0 = (blockIdx.x & 31) * ITILE;

    const float4* h4 = (const float4*)(head + ((size_t)b * SEQ + i0) * DIM);
    const float4* d4 = (const float4*)(dep  + ((size_t)b * SEQ + i0) * DIM);
    #pragma unroll
    for (int u = t; u < ITILE * (DIM / 4); u += 256) {
        const int row = u >> 7, col = u & 127;
        const int sc  = col ^ (row & 7);
        sh[row * 128 + sc] = h4[u];
        sd[row * 128 + sc] = d4[u];
    }
    __syncthreads();

    const int iL = t & 15;
    const int lg = t >> 4;
    const int xm = iL & 7;
    const float4* W4 = (const float4*)W;

    float acch[4] = {0.f, 0.f, 0.f, 0.f};
    float accd[4] = {0.f, 0.f, 0.f, 0.f};
    for (int k4 = 0; k4 < DIM / 4; ++k4) {
        const float4 hv = sh[iL * 128 + (k4 ^ xm)];
        const float4 dv = sd[iL * 128 + (k4 ^ xm)];
        #pragma unroll
        for (int r = 0; r < 4; ++r) {
            const int l = lg * 4 + r;
            const float4 wh = W4[l * 256 + k4];
            const float4 wd = W4[l * 256 + 128 + k4];
            acch[r] += wh.x * hv.x + wh.y * hv.y + wh.z * hv.z + wh.w * hv.w;
            accd[r] += wd.x * dv.x + wd.y * dv.y + wd.z * dv.z + wd.w * dv.w;
        }
    }

    #pragma unroll
    for (int r = 0; r < 4; ++r) {
        const int l = lg * 4 + r;
        const size_t o = ((size_t)b * NL + l) * SEQ + i0 + iL;
        hbuf[o] = acch[r] + bias[l];           // bias folded into h
        dbuf[o] = accd[r];
    }
}

// Kernel 2 v3: block = (b,l,quarter). One-time LDS preload of h-segment
// (128 floats) + d-row (512 floats); d hoisted to a loop-invariant register.
// Steady state = ds_read_b32(broadcast) + v_add x4 + plain store. NO global
// loads in the store loop -> nothing depends on a thrashed L2.
__global__ __launch_bounds__(256) void alab_bcast3(
    const float* __restrict__ hbuf, const float* __restrict__ dbuf,
    float* __restrict__ out)
{
    __shared__ float sh[SEQ / 4];    // 128 h values (this quarter's rows)
    __shared__ f32x4 sd4[SEQ / 4];   // full d row, as float4
    const int t  = threadIdx.x;
    const int q  = blockIdx.x & 3;
    const int bl = blockIdx.x >> 2;             // b*NL + l

    if (t < 128) sh[t] = hbuf[(size_t)bl * SEQ + q * 128 + t];
    ((float*)sd4)[t]       = dbuf[(size_t)bl * SEQ + t];
    ((float*)sd4)[t + 256] = dbuf[(size_t)bl * SEQ + t + 256];
    __syncthreads();

    const int j4 = t & 127;                     // float4 column, fixed
    const int rh = t >> 7;                      // row parity (0/1)
    const f32x4 dreg = sd4[j4];                 // loop-invariant
    f32x4* ob = (f32x4*)out + ((size_t)bl * SEQ + q * 128) * (SEQ / 4);

    #pragma unroll 8
    for (int ii = 0; ii < 128; ii += 2) {
        const int i = ii + rh;
        const f32x4 o = dreg + sh[i];           // LDS broadcast read
        ob[(size_t)i * (SEQ / 4) + j4] = o;     // plain store through L2
    }
}

extern "C" void kernel_launch(void* const* d_in, const int* in_sizes, int n_in,
                              void* d_out, int out_size, void* d_ws, size_t ws_size,
                              hipStream_t stream) {
    const float* head = (const float*)d_in[0];
    const float* dep  = (const float*)d_in[1];
    const float* W    = (const float*)d_in[2];
    const float* bias = (const float*)d_in[3];
    float* out  = (float*)d_out;
    float* hbuf = (float*)d_ws;                          // 1 MiB
    float* dbuf = hbuf + (size_t)BATCH * NL * SEQ;       // 1 MiB

    alab_proj<<<BATCH * (SEQ / ITILE), 256, 0, stream>>>(head, dep, W, bias, hbuf, dbuf);
    alab_bcast3<<<BATCH * NL * 4, 256, 0, stream>>>(hbuf, dbuf, out);
}

// Round 5
// 130.986 us; speedup vs baseline: 1.6457x; 1.0377x over previous
//
#include <hip/hip_runtime.h>
#include <hip/hip_bf16.h>

#define BATCH 8
#define SEQ   512
#define DIM   512
#define NL    64

typedef float f32x4 __attribute__((ext_vector_type(4)));

// proj v2: grid = 8 b x 32 itile16 x 2 (h|d) = 512 blocks, 256 threads.
// Block stages 16 rows of head|dep (32 KB LDS), then computes the 16x64
// (i,l) output tile. Wave w owns l in [w*16, w*16+16); lanes = 16 i x 4 li;
// thread register-tiles s=0..3 -> l = w*16 + li*4 + s.
// W4 load address is uniform across the 16 i-lanes -> 4 lines/instr
// (broadcast), and each W element is read exactly ONCE per block:
// 128 KB/block, 64 MiB total (vs 1 GiB in v1).
__global__ __launch_bounds__(256) void alab_proj2(
    const float* __restrict__ head, const float* __restrict__ dep,
    const float* __restrict__ W, const float* __restrict__ bias,
    float* __restrict__ hbuf, float* __restrict__ dbuf)
{
    __shared__ float4 srow[16][129];            // 16 x 512 f32, +16B row pad
    const int bid   = blockIdx.x;
    const int hd    = bid & 1;                  // 0 = head->h, 1 = dep->d
    const int itile = (bid >> 1) & 31;
    const int b     = bid >> 6;
    const int i0    = itile * 16;

    const float* src  = hd ? dep  : head;
    float*       dst  = hd ? dbuf : hbuf;
    const int    wofs = hd ? 128  : 0;          // float4 offset into W row

    // stage 16 contiguous rows (32 KB), coalesced float4
    const float4* s4 = (const float4*)(src + ((size_t)b * SEQ + i0) * DIM);
    #pragma unroll
    for (int u = threadIdx.x; u < 16 * 128; u += 256)
        srow[u >> 7][u & 127] = s4[u];
    __syncthreads();

    const int lane = threadIdx.x & 63;
    const int w    = threadIdx.x >> 6;          // 0..3
    const int i    = lane & 15;
    const int li   = lane >> 4;                 // 0..3
    const int lb   = w * 16 + li * 4;           // l = lb + s

    const f32x4* W4 = (const f32x4*)W;          // [NL][256] f32x4
    f32x4 a0 = {0.f,0.f,0.f,0.f}, a1 = {0.f,0.f,0.f,0.f};
    f32x4 a2 = {0.f,0.f,0.f,0.f}, a3 = {0.f,0.f,0.f,0.f};

    #pragma unroll 4
    for (int k4 = 0; k4 < 128; ++k4) {
        const f32x4 hv = *(const f32x4*)&srow[i][k4];
        const size_t wb = (size_t)lb * 256 + wofs + k4;
        a0 += hv * W4[wb];
        a1 += hv * W4[wb + 256];
        a2 += hv * W4[wb + 512];
        a3 += hv * W4[wb + 768];
    }

    float r[4] = { a0.x + a0.y + a0.z + a0.w,
                   a1.x + a1.y + a1.z + a1.w,
                   a2.x + a2.y + a2.z + a2.w,
                   a3.x + a3.y + a3.z + a3.w };
    #pragma unroll
    for (int s = 0; s < 4; ++s) {
        const int l = lb + s;
        const float v = r[s] + (hd ? 0.f : bias[l]);   // bias folded into h
        dst[((size_t)b * NL + l) * SEQ + i0 + i] = v;
    }
}

// bcast3 — byte-identical to round 4 (single-variable discipline).
__global__ __launch_bounds__(256) void alab_bcast3(
    const float* __restrict__ hbuf, const float* __restrict__ dbuf,
    float* __restrict__ out)
{
    __shared__ float sh[SEQ / 4];    // 128 h values (this quarter's rows)
    __shared__ f32x4 sd4[SEQ / 4];   // full d row, as float4
    const int t  = threadIdx.x;
    const int q  = blockIdx.x & 3;
    const int bl = blockIdx.x >> 2;             // b*NL + l

    if (t < 128) sh[t] = hbuf[(size_t)bl * SEQ + q * 128 + t];
    ((float*)sd4)[t]       = dbuf[(size_t)bl * SEQ + t];
    ((float*)sd4)[t + 256] = dbuf[(size_t)bl * SEQ + t + 256];
    __syncthreads();

    const int j4 = t & 127;                     // float4 column, fixed
    const int rh = t >> 7;                      // row parity (0/1)
    const f32x4 dreg = sd4[j4];                 // loop-invariant
    f32x4* ob = (f32x4*)out + ((size_t)bl * SEQ + q * 128) * (SEQ / 4);

    #pragma unroll 8
    for (int ii = 0; ii < 128; ii += 2) {
        const int i = ii + rh;
        const f32x4 o = dreg + sh[i];           // LDS broadcast read
        ob[(size_t)i * (SEQ / 4) + j4] = o;     // plain store through L2
    }
}

extern "C" void kernel_launch(void* const* d_in, const int* in_sizes, int n_in,
                              void* d_out, int out_size, void* d_ws, size_t ws_size,
                              hipStream_t stream) {
    const float* head = (const float*)d_in[0];
    const float* dep  = (const float*)d_in[1];
    const float* W    = (const float*)d_in[2];
    const float* bias = (const float*)d_in[3];
    float* out  = (float*)d_out;
    float* hbuf = (float*)d_ws;                          // 1 MiB
    float* dbuf = hbuf + (size_t)BATCH * NL * SEQ;       // 1 MiB

    alab_proj2<<<BATCH * 32 * 2, 256, 0, stream>>>(head, dep, W, bias, hbuf, dbuf);
    alab_bcast3<<<BATCH * NL * 4, 256, 0, stream>>>(hbuf, dbuf, out);
}